// Round 4
// baseline (1338.060 us; speedup 1.0000x reference)
//
#include <hip/hip_runtime.h>

#define NN 100000
#define NE 1600000
#define HID 64
#define TXT 384
#define BATCH 1024
#define NBUCK 391   // ceil(NN/256)

__device__ __forceinline__ ushort f2bf(float f) {
  unsigned u = __float_as_uint(f);
  unsigned r = (u + 0x7fffu + ((u >> 16) & 1u)) >> 16;  // round-to-nearest-even
  return (ushort)r;
}
__device__ __forceinline__ float bf2f(ushort u) {
  return __uint_as_float(((unsigned)u) << 16);
}

// ---------------- P1: bucket histograms (per-block LDS, then global add) -----
__global__ void p_hist(const int* __restrict__ src, const int* __restrict__ dst,
                       int* __restrict__ bcnt_f, int* __restrict__ bcnt_r) {
  __shared__ int hf[NBUCK], hr[NBUCK];
  for (int i = threadIdx.x; i < NBUCK; i += 256) { hf[i] = 0; hr[i] = 0; }
  __syncthreads();
  for (int e = blockIdx.x * 256 + threadIdx.x; e < NE; e += gridDim.x * 256) {
    atomicAdd(&hf[dst[e] >> 8], 1);
    atomicAdd(&hr[src[e] >> 8], 1);
  }
  __syncthreads();
  for (int i = threadIdx.x; i < NBUCK; i += 256) {
    if (hf[i]) atomicAdd(&bcnt_f[i], hf[i]);
    if (hr[i]) atomicAdd(&bcnt_r[i], hr[i]);
  }
}

// ---------------- P2: exclusive scan of bucket counts (one block) ------------
__global__ void p_scan(const int* __restrict__ bcnt_f, const int* __restrict__ bcnt_r,
                       int* __restrict__ bbase_f, int* __restrict__ bcur_f,
                       int* __restrict__ bbase_r, int* __restrict__ bcur_r) {
  __shared__ int tmp[512];
  const int t = threadIdx.x;
  // forward
  int h = (t < NBUCK) ? bcnt_f[t] : 0;
  tmp[t] = h; __syncthreads();
  for (int d = 1; d < 512; d <<= 1) {
    int v = tmp[t]; if (t >= d) v += tmp[t - d];
    __syncthreads(); tmp[t] = v; __syncthreads();
  }
  if (t < NBUCK) { int e = tmp[t] - h; bbase_f[t] = e; bcur_f[t] = e; }
  __syncthreads();
  // reverse
  h = (t < NBUCK) ? bcnt_r[t] : 0;
  tmp[t] = h; __syncthreads();
  for (int d = 1; d < 512; d <<= 1) {
    int v = tmp[t]; if (t >= d) v += tmp[t - d];
    __syncthreads(); tmp[t] = v; __syncthreads();
  }
  if (t < NBUCK) { int e = tmp[t] - h; bbase_r[t] = e; bcur_r[t] = e; }
}

// ---------------- P3: binned scatter (only 2*NBUCK live tails -> L2-hot) -----
// staged record: x = ((node&255)<<24) | col   (col < 2^24), y = weight bits
__global__ void p_scatter(const int* __restrict__ src, const int* __restrict__ dst,
                          const float* __restrict__ w,
                          int* __restrict__ bcur_f, int2* __restrict__ stg_f,
                          int* __restrict__ bcur_r, int2* __restrict__ stg_r) {
  int e = blockIdx.x * 256 + threadIdx.x;
  if (e >= NE) return;
  int s = src[e], d = dst[e];
  int wb = __float_as_int(w[e]);
  int p = atomicAdd(&bcur_f[d >> 8], 1);
  stg_f[p] = make_int2(((d & 255) << 24) | s, wb);
  int q = atomicAdd(&bcur_r[s >> 8], 1);
  stg_r[q] = make_int2(((s & 255) << 24) | d, wb);
}

// ---------------- P4: per-bucket CSR finalize (one block per bucket) ---------
__global__ void p_build(const int2* __restrict__ stgf, const int* __restrict__ bcntf,
                        const int* __restrict__ bbasef,
                        int* __restrict__ startf, int* __restrict__ cntf,
                        int2* __restrict__ cvf,
                        const int2* __restrict__ stgr, const int* __restrict__ bcntr,
                        const int* __restrict__ bbaser,
                        int* __restrict__ startr, int* __restrict__ cntr,
                        int2* __restrict__ cvr) {
  int b = blockIdx.x;
  const int2* stg; const int* bcnt; const int* bbase;
  int* start; int* cnt; int2* cv;
  if (b < NBUCK) { stg = stgf; bcnt = bcntf; bbase = bbasef; start = startf; cnt = cntf; cv = cvf; }
  else { b -= NBUCK; stg = stgr; bcnt = bcntr; bbase = bbaser; start = startr; cnt = cntr; cv = cvr; }
  const int base = bbase[b];
  const int n = bcnt[b];
  const int t = threadIdx.x;
  __shared__ int hist[256], tmp[256], cur[256];
  hist[t] = 0;
  __syncthreads();
  for (int i = t; i < n; i += 256) {
    unsigned pk = (unsigned)stg[base + i].x;
    atomicAdd(&hist[pk >> 24], 1);
  }
  __syncthreads();
  const int h = hist[t];
  tmp[t] = h; __syncthreads();
  for (int d = 1; d < 256; d <<= 1) {
    int v = tmp[t]; if (t >= d) v += tmp[t - d];
    __syncthreads(); tmp[t] = v; __syncthreads();
  }
  const int excl = tmp[t] - h;
  const int node = (b << 8) + t;
  if (node < NN) { start[node] = base + excl; cnt[node] = h; }
  cur[t] = excl;
  __syncthreads();
  for (int i = t; i < n; i += 256) {
    int2 en = stg[base + i];
    unsigned d8 = ((unsigned)en.x) >> 24;
    int pos = atomicAdd(&cur[d8], 1);
    cv[base + pos] = make_int2(en.x & 0xFFFFFF, en.y);
  }
}

// ---------------- weighted-mean aggregation: 2 rows/wave, 32 lanes/row -------
// each thread loads a uint (2 bf16 features); 8 independent row-loads in
// flight per wave (4-unroll x 2 rows)
__global__ void k_gather(const ushort* __restrict__ xb,
                         const int* __restrict__ start, const int* __restrict__ cnt,
                         const int2* __restrict__ cv,
                         float* __restrict__ out) {
  int t = blockIdx.x * blockDim.x + threadIdx.x;
  int row = t >> 5;
  int l2 = (t & 31) * 2;
  if (row >= NN) return;
  int s = start[row];
  int c = cnt[row];
  int e = s + c;
  float ax = 0.f, ay = 0.f;
  int j = s;
  for (; j + 4 <= e; j += 4) {
    int2 e0 = cv[j], e1 = cv[j + 1], e2 = cv[j + 2], e3 = cv[j + 3];
    uint v0 = *(const uint*)(xb + (size_t)e0.x * 64 + l2);
    uint v1 = *(const uint*)(xb + (size_t)e1.x * 64 + l2);
    uint v2 = *(const uint*)(xb + (size_t)e2.x * 64 + l2);
    uint v3 = *(const uint*)(xb + (size_t)e3.x * 64 + l2);
    float w0 = __int_as_float(e0.y), w1 = __int_as_float(e1.y);
    float w2 = __int_as_float(e2.y), w3 = __int_as_float(e3.y);
    ax += w0 * bf2f((ushort)v0); ay += w0 * bf2f((ushort)(v0 >> 16));
    ax += w1 * bf2f((ushort)v1); ay += w1 * bf2f((ushort)(v1 >> 16));
    ax += w2 * bf2f((ushort)v2); ay += w2 * bf2f((ushort)(v2 >> 16));
    ax += w3 * bf2f((ushort)v3); ay += w3 * bf2f((ushort)(v3 >> 16));
  }
  for (; j < e; ++j) {
    int2 ee = cv[j];
    uint v = *(const uint*)(xb + (size_t)ee.x * 64 + l2);
    float ww = __int_as_float(ee.y);
    ax += ww * bf2f((ushort)v); ay += ww * bf2f((ushort)(v >> 16));
  }
  float inv = (c > 0) ? 1.0f / (float)c : 0.f;   // DGL mean; zero in-degree -> 0
  *(float2*)(out + (size_t)row * 64 + l2) = make_float2(ax * inv, ay * inv);
}

// ---------------- encoder GEMM: [NN,384]@[384,64]+b -> x (+ bf16 mirror) -----
__launch_bounds__(256)
__global__ void k_enc(const float* __restrict__ T, const float* __restrict__ W,
                      const float* __restrict__ bias, float* __restrict__ x,
                      ushort* __restrict__ xb) {
  __shared__ float As[32][256];
  __shared__ float Bs[32][64];
  const int tid = threadIdx.x;
  const int row0 = blockIdx.x * 256;
  const int rg = tid >> 3, cg = tid & 7;
  float acc[8][8] = {};
  #pragma unroll 1
  for (int ch = 0; ch < 12; ++ch) {
    const int kc = ch * 32;
    const int arow = row0 + tid;
    if (arow < NN) {
      const float* p = T + (size_t)arow * TXT + kc;
      #pragma unroll
      for (int j = 0; j < 32; j += 4) {
        float4 v = *(const float4*)(p + j);
        As[j + 0][tid] = v.x; As[j + 1][tid] = v.y;
        As[j + 2][tid] = v.z; As[j + 3][tid] = v.w;
      }
    } else {
      #pragma unroll
      for (int j = 0; j < 32; ++j) As[j][tid] = 0.f;
    }
    {
      const int i = tid * 8, k = i >> 6, c = i & 63;
      float4 v0 = *(const float4*)(W + (kc + k) * 64 + c);
      float4 v1 = *(const float4*)(W + (kc + k) * 64 + c + 4);
      *(float4*)&Bs[k][c] = v0; *(float4*)&Bs[k][c + 4] = v1;
    }
    __syncthreads();
    #pragma unroll 4
    for (int k = 0; k < 32; ++k) {
      float4 a0 = *(const float4*)&As[k][rg * 8];
      float4 a1 = *(const float4*)&As[k][rg * 8 + 4];
      float4 b0 = *(const float4*)&Bs[k][cg * 8];
      float4 b1 = *(const float4*)&Bs[k][cg * 8 + 4];
      const float a[8] = {a0.x, a0.y, a0.z, a0.w, a1.x, a1.y, a1.z, a1.w};
      const float b[8] = {b0.x, b0.y, b0.z, b0.w, b1.x, b1.y, b1.z, b1.w};
      #pragma unroll
      for (int i = 0; i < 8; ++i)
        #pragma unroll
        for (int jj = 0; jj < 8; ++jj)
          acc[i][jj] = fmaf(a[i], b[jj], acc[i][jj]);
    }
    __syncthreads();
  }
  #pragma unroll
  for (int i = 0; i < 8; ++i) {
    const int row = row0 + rg * 8 + i;
    if (row >= NN) continue;
    float v[8];
    #pragma unroll
    for (int j = 0; j < 8; ++j) v[j] = acc[i][j] + bias[cg * 8 + j];
    float* xp = x + (size_t)row * 64 + cg * 8;
    *(float4*)xp = make_float4(v[0], v[1], v[2], v[3]);
    *(float4*)(xp + 4) = make_float4(v[4], v[5], v[6], v[7]);
    uint p4[4];
    #pragma unroll
    for (int j = 0; j < 4; ++j)
      p4[j] = (uint)f2bf(v[2 * j]) | ((uint)f2bf(v[2 * j + 1]) << 16);
    *(uint4*)(xb + (size_t)row * 64 + cg * 8) = make_uint4(p4[0], p4[1], p4[2], p4[3]);
  }
}

// ---------------- per-direction combine GEMM: [NN,128]@[128,64] --------------
// A = [x | n]; B = [Wself ; Wneigh].
// mode 0: n := relu(acc + bias)   (in-place over neigh buffer, block-local rows)
// mode 1: x += yrel + relu(acc + bias); xb := bf16(x)
__launch_bounds__(256)
__global__ void k_gemm(const float* __restrict__ A1, float* __restrict__ n,
                       const float* __restrict__ yrel,
                       const float* __restrict__ B1, const float* __restrict__ B2,
                       const float* __restrict__ bias,
                       float* __restrict__ x, ushort* __restrict__ xb, int mode) {
  __shared__ float As[32][256];
  __shared__ float Bs[32][64];
  const int tid = threadIdx.x;
  const int row0 = blockIdx.x * 256;
  const int rg = tid >> 3, cg = tid & 7;
  float acc[8][8] = {};
  #pragma unroll 1
  for (int ch = 0; ch < 4; ++ch) {
    const float* Asrc = (ch < 2) ? A1 : n;
    const float* Bsrc = (ch < 2) ? B1 : B2;
    const int kc = (ch & 1) * 32;
    const int arow = row0 + tid;
    if (arow < NN) {
      const float* p = Asrc + (size_t)arow * 64 + kc;
      #pragma unroll
      for (int j = 0; j < 32; j += 4) {
        float4 v = *(const float4*)(p + j);
        As[j + 0][tid] = v.x; As[j + 1][tid] = v.y;
        As[j + 2][tid] = v.z; As[j + 3][tid] = v.w;
      }
    } else {
      #pragma unroll
      for (int j = 0; j < 32; ++j) As[j][tid] = 0.f;
    }
    {
      const int i = tid * 8, k = i >> 6, c = i & 63;
      float4 v0 = *(const float4*)(Bsrc + (kc + k) * 64 + c);
      float4 v1 = *(const float4*)(Bsrc + (kc + k) * 64 + c + 4);
      *(float4*)&Bs[k][c] = v0; *(float4*)&Bs[k][c + 4] = v1;
    }
    __syncthreads();
    #pragma unroll 4
    for (int k = 0; k < 32; ++k) {
      float4 a0 = *(const float4*)&As[k][rg * 8];
      float4 a1 = *(const float4*)&As[k][rg * 8 + 4];
      float4 b0 = *(const float4*)&Bs[k][cg * 8];
      float4 b1 = *(const float4*)&Bs[k][cg * 8 + 4];
      const float a[8] = {a0.x, a0.y, a0.z, a0.w, a1.x, a1.y, a1.z, a1.w};
      const float b[8] = {b0.x, b0.y, b0.z, b0.w, b1.x, b1.y, b1.z, b1.w};
      #pragma unroll
      for (int i = 0; i < 8; ++i)
        #pragma unroll
        for (int jj = 0; jj < 8; ++jj)
          acc[i][jj] = fmaf(a[i], b[jj], acc[i][jj]);
    }
    __syncthreads();
  }
  #pragma unroll
  for (int i = 0; i < 8; ++i) {
    const int row = row0 + rg * 8 + i;
    if (row >= NN) continue;
    const int c0 = cg * 8;
    float vv[8];
    #pragma unroll
    for (int j = 0; j < 8; ++j) vv[j] = acc[i][j] + bias[c0 + j];
    if (mode == 0) {
      float* np = n + (size_t)row * 64 + c0;
      *(float4*)np = make_float4(fmaxf(vv[0], 0.f), fmaxf(vv[1], 0.f),
                                 fmaxf(vv[2], 0.f), fmaxf(vv[3], 0.f));
      *(float4*)(np + 4) = make_float4(fmaxf(vv[4], 0.f), fmaxf(vv[5], 0.f),
                                       fmaxf(vv[6], 0.f), fmaxf(vv[7], 0.f));
    } else {
      size_t base = (size_t)row * 64 + c0;
      float nv[8];
      float4 nf0 = *(const float4*)(yrel + base);
      float4 nf1 = *(const float4*)(yrel + base + 4);
      nv[0] = nf0.x; nv[1] = nf0.y; nv[2] = nf0.z; nv[3] = nf0.w;
      nv[4] = nf1.x; nv[5] = nf1.y; nv[6] = nf1.z; nv[7] = nf1.w;
      float xv[8];
      float4 x0 = *(const float4*)(x + base);
      float4 x1 = *(const float4*)(x + base + 4);
      xv[0] = x0.x; xv[1] = x0.y; xv[2] = x0.z; xv[3] = x0.w;
      xv[4] = x1.x; xv[5] = x1.y; xv[6] = x1.z; xv[7] = x1.w;
      float o[8];
      #pragma unroll
      for (int j = 0; j < 8; ++j) o[j] = xv[j] + nv[j] + fmaxf(vv[j], 0.f);
      *(float4*)(x + base) = make_float4(o[0], o[1], o[2], o[3]);
      *(float4*)(x + base + 4) = make_float4(o[4], o[5], o[6], o[7]);
      uint p4[4];
      #pragma unroll
      for (int j = 0; j < 4; ++j)
        p4[j] = (uint)f2bf(o[2 * j]) | ((uint)f2bf(o[2 * j + 1]) << 16);
      *(uint4*)(xb + base) = make_uint4(p4[0], p4[1], p4[2], p4[3]);
    }
  }
}

// ---------------- output gather + L2 normalize -------------------------------
__global__ void k_out(const float* __restrict__ x, const int* __restrict__ ids,
                      float* __restrict__ out) {
  int b = (blockIdx.x * blockDim.x + threadIdx.x) >> 6;
  int lane = threadIdx.x & 63;
  if (b >= BATCH) return;
  int row = ids[b];
  float v = x[(size_t)row * 64 + lane];
  float s = v * v;
  #pragma unroll
  for (int m = 1; m < 64; m <<= 1) s += __shfl_xor(s, m);
  out[b * 64 + lane] = v / sqrtf(s);
}

extern "C" void kernel_launch(void* const* d_in, const int* in_sizes, int n_in,
                              void* d_out, int out_size, void* d_ws, size_t ws_size,
                              hipStream_t stream) {
  const float* text = (const float*)d_in[0];
  const float* wts  = (const float*)d_in[1];
  const float* Wenc = (const float*)d_in[2];
  const float* benc = (const float*)d_in[3];
  const float* Wsf  = (const float*)d_in[4];
  const float* Wnf  = (const float*)d_in[5];
  const float* bf   = (const float*)d_in[6];
  const float* Wsr  = (const float*)d_in[7];
  const float* Wnr  = (const float*)d_in[8];
  const float* br   = (const float*)d_in[9];
  const int*   src  = (const int*)d_in[10];
  const int*   dst  = (const int*)d_in[11];
  const int*   ids  = (const int*)d_in[12];
  float* out = (float*)d_out;

  char* ws = (char*)d_ws;
  size_t o = 0;
  auto alloc = [&](size_t f32elems) {
    void* p = ws + o;
    o += f32elems * 4;
    o = (o + 255) & ~(size_t)255;
    return p;
  };
  float*  x   = (float*)alloc((size_t)NN * 64);
  float*  nf  = (float*)alloc((size_t)NN * 64);   // also aliased as stage_f
  float*  nr  = (float*)alloc((size_t)NN * 64);   // also aliased as stage_r
  ushort* xb  = (ushort*)alloc((size_t)NN * 32);  // bf16 mirror of x
  int2*   cvf = (int2*)alloc((size_t)NE * 2);     // final CSR (col, weight)
  int2*   cvr = (int2*)alloc((size_t)NE * 2);
  // ---- zero region: bucket counts (2*NBUCK ints, one memset) ----
  int* bcnt_f = (int*)alloc(2 * NBUCK);
  int* bcnt_r = bcnt_f + NBUCK;
  // ---- end zero region ----
  int* bbase_f = (int*)alloc(NBUCK);
  int* bcur_f  = (int*)alloc(NBUCK);
  int* bbase_r = (int*)alloc(NBUCK);
  int* bcur_r  = (int*)alloc(NBUCK);
  int* startf  = (int*)alloc(NN);
  int* cntf    = (int*)alloc(NN);
  int* startr  = (int*)alloc(NN);
  int* cntr    = (int*)alloc(NN);

  int2* stg_f = (int2*)nf;   // staging dead before first gather writes nf
  int2* stg_r = (int2*)nr;

  hipMemsetAsync(bcnt_f, 0, 2 * NBUCK * sizeof(int), stream);

  const int EB = (NE + 255) / 256;
  const int VB = (NN + 255) / 256;

  p_hist<<<512, 256, 0, stream>>>(src, dst, bcnt_f, bcnt_r);
  p_scan<<<1, 512, 0, stream>>>(bcnt_f, bcnt_r, bbase_f, bcur_f, bbase_r, bcur_r);
  p_scatter<<<EB, 256, 0, stream>>>(src, dst, wts, bcur_f, stg_f, bcur_r, stg_r);
  p_build<<<2 * NBUCK, 256, 0, stream>>>(stg_f, bcnt_f, bbase_f, startf, cntf, cvf,
                                         stg_r, bcnt_r, bbase_r, startr, cntr, cvr);
  k_enc<<<VB, 256, 0, stream>>>(text, Wenc, benc, x, xb);

  const int GB = ((size_t)NN * 32 + 255) / 256;  // 2 rows per wave
  for (int l = 0; l < 2; ++l) {
    const float* Wsf_l = Wsf + l * HID * HID;
    const float* Wnf_l = Wnf + l * HID * HID;
    const float* Wsr_l = Wsr + l * HID * HID;
    const float* Wnr_l = Wnr + l * HID * HID;
    const float* bf_l  = bf + l * HID;
    const float* br_l  = br + l * HID;
    k_gather<<<GB, 256, 0, stream>>>(xb, startf, cntf, cvf, nf);
    k_gather<<<GB, 256, 0, stream>>>(xb, startr, cntr, cvr, nr);
    // mode 0: nf := relu(y_f)
    k_gemm<<<VB, 256, 0, stream>>>(x, nf, nf, Wsf_l, Wnf_l, bf_l, x, xb, 0);
    // mode 1: x += nf (=relu(y_f)) + relu(y_r)
    k_gemm<<<VB, 256, 0, stream>>>(x, nr, nf, Wsr_l, Wnr_l, br_l, x, xb, 1);
  }
  k_out<<<(BATCH * 64) / 256, 256, 0, stream>>>(x, ids, out);
}

// Round 5
// 730.780 us; speedup vs baseline: 1.8310x; 1.8310x over previous
//
#include <hip/hip_runtime.h>

#define NN 100000
#define NE 1600000
#define HID 64
#define TXT 384
#define BATCH 1024
#define NBUCK 391        // ceil(NN/256)
#define SBLK 256         // scatter/hist blocks
#define EPB ((NE + SBLK - 1) / SBLK)   // edges per block = 6250

__device__ __forceinline__ ushort f2bf(float f) {
  unsigned u = __float_as_uint(f);
  unsigned r = (u + 0x7fffu + ((u >> 16) & 1u)) >> 16;  // round-to-nearest-even
  return (ushort)r;
}
__device__ __forceinline__ float bf2f(ushort u) {
  return __uint_as_float(((unsigned)u) << 16);
}

// ---- P1: per-(block,bucket) histogram matrix; no global atomics, no memset --
__global__ void k_hist2(const int* __restrict__ src, const int* __restrict__ dst,
                        int* __restrict__ cm_f, int* __restrict__ cm_r) {
  __shared__ int hf[NBUCK], hr[NBUCK];
  const int t = threadIdx.x, blk = blockIdx.x;
  for (int i = t; i < NBUCK; i += 256) { hf[i] = 0; hr[i] = 0; }
  __syncthreads();
  const int e0 = blk * EPB, e1 = min(NE, e0 + EPB);
  for (int e = e0 + t; e < e1; e += 256) {
    atomicAdd(&hf[dst[e] >> 8], 1);
    atomicAdd(&hr[src[e] >> 8], 1);
  }
  __syncthreads();
  for (int i = t; i < NBUCK; i += 256) {
    cm_f[i * SBLK + blk] = hf[i];
    cm_r[i * SBLK + blk] = hr[i];
  }
}

// ---- P2a: per-bucket exclusive scan over the 256 block-counts (in place) ----
__global__ void k_scan1(int* __restrict__ cm_f, int* __restrict__ cm_r,
                        int* __restrict__ btot) {
  __shared__ int tmp[256];
  const int t = threadIdx.x;
  int b = blockIdx.x;
  int* cm = (b < NBUCK) ? cm_f : cm_r;
  int bucket = (b < NBUCK) ? b : b - NBUCK;
  int* row = cm + bucket * SBLK;
  int v = row[t];
  tmp[t] = v; __syncthreads();
  for (int d = 1; d < 256; d <<= 1) {
    int s = tmp[t]; if (t >= d) s += tmp[t - d];
    __syncthreads(); tmp[t] = s; __syncthreads();
  }
  row[t] = tmp[t] - v;                 // exclusive prefix
  if (t == 255) btot[b] = tmp[t];      // bucket total
}

// ---- P2b: exclusive scan of bucket totals -> bucket bases -------------------
__global__ void k_scan2(const int* __restrict__ btot,
                        int* __restrict__ bbase_f, int* __restrict__ bbase_r) {
  __shared__ int tmp[512];
  const int t = threadIdx.x;
  int h = (t < NBUCK) ? btot[t] : 0;
  tmp[t] = h; __syncthreads();
  for (int d = 1; d < 512; d <<= 1) {
    int v = tmp[t]; if (t >= d) v += tmp[t - d];
    __syncthreads(); tmp[t] = v; __syncthreads();
  }
  if (t < NBUCK) bbase_f[t] = tmp[t] - h;
  __syncthreads();
  h = (t < NBUCK) ? btot[NBUCK + t] : 0;
  tmp[t] = h; __syncthreads();
  for (int d = 1; d < 512; d <<= 1) {
    int v = tmp[t]; if (t >= d) v += tmp[t - d];
    __syncthreads(); tmp[t] = v; __syncthreads();
  }
  if (t < NBUCK) bbase_r[t] = tmp[t] - h;
}

// ---- P3: scatter with LDS cursors only (zero global atomics) ----------------
// staged record: x = ((node&255)<<24) | col, y = weight bits
__global__ void k_scatter2(const int* __restrict__ src, const int* __restrict__ dst,
                           const float* __restrict__ w,
                           const int* __restrict__ cm_f, const int* __restrict__ cm_r,
                           const int* __restrict__ bbase_f, const int* __restrict__ bbase_r,
                           int2* __restrict__ stg_f, int2* __restrict__ stg_r) {
  __shared__ int cur_f[NBUCK], cur_r[NBUCK];
  const int t = threadIdx.x, blk = blockIdx.x;
  for (int i = t; i < NBUCK; i += 256) {
    cur_f[i] = bbase_f[i] + cm_f[i * SBLK + blk];
    cur_r[i] = bbase_r[i] + cm_r[i * SBLK + blk];
  }
  __syncthreads();
  const int e0 = blk * EPB, e1 = min(NE, e0 + EPB);
  for (int e = e0 + t; e < e1; e += 256) {
    int s = src[e], d = dst[e];
    int wb = __float_as_int(w[e]);
    int p = atomicAdd(&cur_f[d >> 8], 1);
    stg_f[p] = make_int2(((d & 255) << 24) | s, wb);
    int q = atomicAdd(&cur_r[s >> 8], 1);
    stg_r[q] = make_int2(((s & 255) << 24) | d, wb);
  }
}

// ---- P4: per-bucket CSR finalize (one block per bucket) ---------------------
__global__ void p_build(const int2* __restrict__ stgf, const int* __restrict__ btotf,
                        const int* __restrict__ bbasef,
                        int* __restrict__ startf, int* __restrict__ cntf,
                        int2* __restrict__ cvf,
                        const int2* __restrict__ stgr, const int* __restrict__ btotr,
                        const int* __restrict__ bbaser,
                        int* __restrict__ startr, int* __restrict__ cntr,
                        int2* __restrict__ cvr) {
  int b = blockIdx.x;
  const int2* stg; const int* bcnt; const int* bbase;
  int* start; int* cnt; int2* cv;
  if (b < NBUCK) { stg = stgf; bcnt = btotf; bbase = bbasef; start = startf; cnt = cntf; cv = cvf; }
  else { b -= NBUCK; stg = stgr; bcnt = btotr; bbase = bbaser; start = startr; cnt = cntr; cv = cvr; }
  const int base = bbase[b];
  const int n = bcnt[b];
  const int t = threadIdx.x;
  __shared__ int hist[256], tmp[256], cur[256];
  hist[t] = 0;
  __syncthreads();
  for (int i = t; i < n; i += 256) {
    unsigned pk = (unsigned)stg[base + i].x;
    atomicAdd(&hist[pk >> 24], 1);
  }
  __syncthreads();
  const int h = hist[t];
  tmp[t] = h; __syncthreads();
  for (int d = 1; d < 256; d <<= 1) {
    int v = tmp[t]; if (t >= d) v += tmp[t - d];
    __syncthreads(); tmp[t] = v; __syncthreads();
  }
  const int excl = tmp[t] - h;
  const int node = (b << 8) + t;
  if (node < NN) { start[node] = base + excl; cnt[node] = h; }
  cur[t] = excl;
  __syncthreads();
  for (int i = t; i < n; i += 256) {
    int2 en = stg[base + i];
    unsigned d8 = ((unsigned)en.x) >> 24;
    int pos = atomicAdd(&cur[d8], 1);
    cv[base + pos] = make_int2(en.x & 0xFFFFFF, en.y);
  }
}

// ---- weighted-mean aggregation: 2 rows/wave, 32 lanes/row, bf16 reads -------
__global__ void k_gather(const ushort* __restrict__ xb,
                         const int* __restrict__ start, const int* __restrict__ cnt,
                         const int2* __restrict__ cv,
                         float* __restrict__ out) {
  int t = blockIdx.x * blockDim.x + threadIdx.x;
  int row = t >> 5;
  int l2 = (t & 31) * 2;
  if (row >= NN) return;
  int s = start[row];
  int c = cnt[row];
  int e = s + c;
  float ax = 0.f, ay = 0.f;
  int j = s;
  for (; j + 4 <= e; j += 4) {
    int2 e0 = cv[j], e1 = cv[j + 1], e2 = cv[j + 2], e3 = cv[j + 3];
    uint v0 = *(const uint*)(xb + (size_t)e0.x * 64 + l2);
    uint v1 = *(const uint*)(xb + (size_t)e1.x * 64 + l2);
    uint v2 = *(const uint*)(xb + (size_t)e2.x * 64 + l2);
    uint v3 = *(const uint*)(xb + (size_t)e3.x * 64 + l2);
    float w0 = __int_as_float(e0.y), w1 = __int_as_float(e1.y);
    float w2 = __int_as_float(e2.y), w3 = __int_as_float(e3.y);
    ax += w0 * bf2f((ushort)v0); ay += w0 * bf2f((ushort)(v0 >> 16));
    ax += w1 * bf2f((ushort)v1); ay += w1 * bf2f((ushort)(v1 >> 16));
    ax += w2 * bf2f((ushort)v2); ay += w2 * bf2f((ushort)(v2 >> 16));
    ax += w3 * bf2f((ushort)v3); ay += w3 * bf2f((ushort)(v3 >> 16));
  }
  for (; j < e; ++j) {
    int2 ee = cv[j];
    uint v = *(const uint*)(xb + (size_t)ee.x * 64 + l2);
    float ww = __int_as_float(ee.y);
    ax += ww * bf2f((ushort)v); ay += ww * bf2f((ushort)(v >> 16));
  }
  float inv = (c > 0) ? 1.0f / (float)c : 0.f;   // DGL mean; zero in-degree -> 0
  *(float2*)(out + (size_t)row * 64 + l2) = make_float2(ax * inv, ay * inv);
}

// ---- encoder GEMM: [NN,384]@[384,64]+b -> x (+ bf16 mirror) -----------------
__launch_bounds__(256)
__global__ void k_enc(const float* __restrict__ T, const float* __restrict__ W,
                      const float* __restrict__ bias, float* __restrict__ x,
                      ushort* __restrict__ xb) {
  __shared__ float As[32][256];
  __shared__ float Bs[32][64];
  const int tid = threadIdx.x;
  const int row0 = blockIdx.x * 256;
  const int rg = tid >> 3, cg = tid & 7;
  float acc[8][8] = {};
  #pragma unroll 1
  for (int ch = 0; ch < 12; ++ch) {
    const int kc = ch * 32;
    const int arow = row0 + tid;
    if (arow < NN) {
      const float* p = T + (size_t)arow * TXT + kc;
      #pragma unroll
      for (int j = 0; j < 32; j += 4) {
        float4 v = *(const float4*)(p + j);
        As[j + 0][tid] = v.x; As[j + 1][tid] = v.y;
        As[j + 2][tid] = v.z; As[j + 3][tid] = v.w;
      }
    } else {
      #pragma unroll
      for (int j = 0; j < 32; ++j) As[j][tid] = 0.f;
    }
    {
      const int i = tid * 8, k = i >> 6, c = i & 63;
      float4 v0 = *(const float4*)(W + (kc + k) * 64 + c);
      float4 v1 = *(const float4*)(W + (kc + k) * 64 + c + 4);
      *(float4*)&Bs[k][c] = v0; *(float4*)&Bs[k][c + 4] = v1;
    }
    __syncthreads();
    #pragma unroll 4
    for (int k = 0; k < 32; ++k) {
      float4 a0 = *(const float4*)&As[k][rg * 8];
      float4 a1 = *(const float4*)&As[k][rg * 8 + 4];
      float4 b0 = *(const float4*)&Bs[k][cg * 8];
      float4 b1 = *(const float4*)&Bs[k][cg * 8 + 4];
      const float a[8] = {a0.x, a0.y, a0.z, a0.w, a1.x, a1.y, a1.z, a1.w};
      const float b[8] = {b0.x, b0.y, b0.z, b0.w, b1.x, b1.y, b1.z, b1.w};
      #pragma unroll
      for (int i = 0; i < 8; ++i)
        #pragma unroll
        for (int jj = 0; jj < 8; ++jj)
          acc[i][jj] = fmaf(a[i], b[jj], acc[i][jj]);
    }
    __syncthreads();
  }
  #pragma unroll
  for (int i = 0; i < 8; ++i) {
    const int row = row0 + rg * 8 + i;
    if (row >= NN) continue;
    float v[8];
    #pragma unroll
    for (int j = 0; j < 8; ++j) v[j] = acc[i][j] + bias[cg * 8 + j];
    float* xp = x + (size_t)row * 64 + cg * 8;
    *(float4*)xp = make_float4(v[0], v[1], v[2], v[3]);
    *(float4*)(xp + 4) = make_float4(v[4], v[5], v[6], v[7]);
    uint p4[4];
    #pragma unroll
    for (int j = 0; j < 4; ++j)
      p4[j] = (uint)f2bf(v[2 * j]) | ((uint)f2bf(v[2 * j + 1]) << 16);
    *(uint4*)(xb + (size_t)row * 64 + cg * 8) = make_uint4(p4[0], p4[1], p4[2], p4[3]);
  }
}

// ---- per-direction combine GEMM: [NN,128]@[128,64] --------------------------
// mode 0: n := relu(acc + bias)   mode 1: x += yrel + relu(acc + bias); xb=bf16(x)
__launch_bounds__(256)
__global__ void k_gemm(const float* __restrict__ A1, float* __restrict__ n,
                       const float* __restrict__ yrel,
                       const float* __restrict__ B1, const float* __restrict__ B2,
                       const float* __restrict__ bias,
                       float* __restrict__ x, ushort* __restrict__ xb, int mode) {
  __shared__ float As[32][256];
  __shared__ float Bs[32][64];
  const int tid = threadIdx.x;
  const int row0 = blockIdx.x * 256;
  const int rg = tid >> 3, cg = tid & 7;
  float acc[8][8] = {};
  #pragma unroll 1
  for (int ch = 0; ch < 4; ++ch) {
    const float* Asrc = (ch < 2) ? A1 : n;
    const float* Bsrc = (ch < 2) ? B1 : B2;
    const int kc = (ch & 1) * 32;
    const int arow = row0 + tid;
    if (arow < NN) {
      const float* p = Asrc + (size_t)arow * 64 + kc;
      #pragma unroll
      for (int j = 0; j < 32; j += 4) {
        float4 v = *(const float4*)(p + j);
        As[j + 0][tid] = v.x; As[j + 1][tid] = v.y;
        As[j + 2][tid] = v.z; As[j + 3][tid] = v.w;
      }
    } else {
      #pragma unroll
      for (int j = 0; j < 32; ++j) As[j][tid] = 0.f;
    }
    {
      const int i = tid * 8, k = i >> 6, c = i & 63;
      float4 v0 = *(const float4*)(Bsrc + (kc + k) * 64 + c);
      float4 v1 = *(const float4*)(Bsrc + (kc + k) * 64 + c + 4);
      *(float4*)&Bs[k][c] = v0; *(float4*)&Bs[k][c + 4] = v1;
    }
    __syncthreads();
    #pragma unroll 4
    for (int k = 0; k < 32; ++k) {
      float4 a0 = *(const float4*)&As[k][rg * 8];
      float4 a1 = *(const float4*)&As[k][rg * 8 + 4];
      float4 b0 = *(const float4*)&Bs[k][cg * 8];
      float4 b1 = *(const float4*)&Bs[k][cg * 8 + 4];
      const float a[8] = {a0.x, a0.y, a0.z, a0.w, a1.x, a1.y, a1.z, a1.w};
      const float b[8] = {b0.x, b0.y, b0.z, b0.w, b1.x, b1.y, b1.z, b1.w};
      #pragma unroll
      for (int i = 0; i < 8; ++i)
        #pragma unroll
        for (int jj = 0; jj < 8; ++jj)
          acc[i][jj] = fmaf(a[i], b[jj], acc[i][jj]);
    }
    __syncthreads();
  }
  #pragma unroll
  for (int i = 0; i < 8; ++i) {
    const int row = row0 + rg * 8 + i;
    if (row >= NN) continue;
    const int c0 = cg * 8;
    float vv[8];
    #pragma unroll
    for (int j = 0; j < 8; ++j) vv[j] = acc[i][j] + bias[c0 + j];
    if (mode == 0) {
      float* np = n + (size_t)row * 64 + c0;
      *(float4*)np = make_float4(fmaxf(vv[0], 0.f), fmaxf(vv[1], 0.f),
                                 fmaxf(vv[2], 0.f), fmaxf(vv[3], 0.f));
      *(float4*)(np + 4) = make_float4(fmaxf(vv[4], 0.f), fmaxf(vv[5], 0.f),
                                       fmaxf(vv[6], 0.f), fmaxf(vv[7], 0.f));
    } else {
      size_t base = (size_t)row * 64 + c0;
      float4 nf0 = *(const float4*)(yrel + base);
      float4 nf1 = *(const float4*)(yrel + base + 4);
      float4 x0 = *(const float4*)(x + base);
      float4 x1 = *(const float4*)(x + base + 4);
      float nv[8] = {nf0.x, nf0.y, nf0.z, nf0.w, nf1.x, nf1.y, nf1.z, nf1.w};
      float xv[8] = {x0.x, x0.y, x0.z, x0.w, x1.x, x1.y, x1.z, x1.w};
      float o[8];
      #pragma unroll
      for (int j = 0; j < 8; ++j) o[j] = xv[j] + nv[j] + fmaxf(vv[j], 0.f);
      *(float4*)(x + base) = make_float4(o[0], o[1], o[2], o[3]);
      *(float4*)(x + base + 4) = make_float4(o[4], o[5], o[6], o[7]);
      uint p4[4];
      #pragma unroll
      for (int j = 0; j < 4; ++j)
        p4[j] = (uint)f2bf(o[2 * j]) | ((uint)f2bf(o[2 * j + 1]) << 16);
      *(uint4*)(xb + base) = make_uint4(p4[0], p4[1], p4[2], p4[3]);
    }
  }
}

// ---- output gather + L2 normalize -------------------------------------------
__global__ void k_out(const float* __restrict__ x, const int* __restrict__ ids,
                      float* __restrict__ out) {
  int b = (blockIdx.x * blockDim.x + threadIdx.x) >> 6;
  int lane = threadIdx.x & 63;
  if (b >= BATCH) return;
  int row = ids[b];
  float v = x[(size_t)row * 64 + lane];
  float s = v * v;
  #pragma unroll
  for (int m = 1; m < 64; m <<= 1) s += __shfl_xor(s, m);
  out[b * 64 + lane] = v / sqrtf(s);
}

extern "C" void kernel_launch(void* const* d_in, const int* in_sizes, int n_in,
                              void* d_out, int out_size, void* d_ws, size_t ws_size,
                              hipStream_t stream) {
  const float* text = (const float*)d_in[0];
  const float* wts  = (const float*)d_in[1];
  const float* Wenc = (const float*)d_in[2];
  const float* benc = (const float*)d_in[3];
  const float* Wsf  = (const float*)d_in[4];
  const float* Wnf  = (const float*)d_in[5];
  const float* bf   = (const float*)d_in[6];
  const float* Wsr  = (const float*)d_in[7];
  const float* Wnr  = (const float*)d_in[8];
  const float* br   = (const float*)d_in[9];
  const int*   src  = (const int*)d_in[10];
  const int*   dst  = (const int*)d_in[11];
  const int*   ids  = (const int*)d_in[12];
  float* out = (float*)d_out;

  char* ws = (char*)d_ws;
  size_t o = 0;
  auto alloc = [&](size_t f32elems) {
    void* p = ws + o;
    o += f32elems * 4;
    o = (o + 255) & ~(size_t)255;
    return p;
  };
  float*  x   = (float*)alloc((size_t)NN * 64);
  float*  nf  = (float*)alloc((size_t)NN * 64);   // aliased as stage_f
  float*  nr  = (float*)alloc((size_t)NN * 64);   // aliased as stage_r
  ushort* xb  = (ushort*)alloc((size_t)NN * 32);  // bf16 mirror of x
  int2*   cvf = (int2*)alloc((size_t)NE * 2);     // final CSR (col, weight)
  int2*   cvr = (int2*)alloc((size_t)NE * 2);
  int* cm_f    = (int*)alloc((size_t)NBUCK * SBLK);  // count/prefix matrix
  int* cm_r    = (int*)alloc((size_t)NBUCK * SBLK);
  int* btot    = (int*)alloc(2 * NBUCK);
  int* bbase_f = (int*)alloc(NBUCK);
  int* bbase_r = (int*)alloc(NBUCK);
  int* startf  = (int*)alloc(NN);
  int* cntf    = (int*)alloc(NN);
  int* startr  = (int*)alloc(NN);
  int* cntr    = (int*)alloc(NN);

  int2* stg_f = (int2*)nf;   // staging dead before first gather writes nf
  int2* stg_r = (int2*)nr;

  const int VB = (NN + 255) / 256;

  k_hist2<<<SBLK, 256, 0, stream>>>(src, dst, cm_f, cm_r);
  k_scan1<<<2 * NBUCK, 256, 0, stream>>>(cm_f, cm_r, btot);
  k_scan2<<<1, 512, 0, stream>>>(btot, bbase_f, bbase_r);
  k_scatter2<<<SBLK, 256, 0, stream>>>(src, dst, wts, cm_f, cm_r,
                                       bbase_f, bbase_r, stg_f, stg_r);
  p_build<<<2 * NBUCK, 256, 0, stream>>>(stg_f, btot, bbase_f, startf, cntf, cvf,
                                         stg_r, btot + NBUCK, bbase_r, startr, cntr, cvr);
  k_enc<<<VB, 256, 0, stream>>>(text, Wenc, benc, x, xb);

  const int GB = ((size_t)NN * 32 + 255) / 256;  // 2 rows per wave
  for (int l = 0; l < 2; ++l) {
    const float* Wsf_l = Wsf + l * HID * HID;
    const float* Wnf_l = Wnf + l * HID * HID;
    const float* Wsr_l = Wsr + l * HID * HID;
    const float* Wnr_l = Wnr + l * HID * HID;
    const float* bf_l  = bf + l * HID;
    const float* br_l  = br + l * HID;
    k_gather<<<GB, 256, 0, stream>>>(xb, startf, cntf, cvf, nf);
    k_gather<<<GB, 256, 0, stream>>>(xb, startr, cntr, cvr, nr);
    // mode 0: nf := relu(y_f)
    k_gemm<<<VB, 256, 0, stream>>>(x, nf, nf, Wsf_l, Wnf_l, bf_l, x, xb, 0);
    // mode 1: x += nf (=relu(y_f)) + relu(y_r)
    k_gemm<<<VB, 256, 0, stream>>>(x, nr, nf, Wsr_l, Wnr_l, br_l, x, xb, 1);
  }
  k_out<<<(BATCH * 64) / 256, 256, 0, stream>>>(x, ids, out);
}

// Round 6
// 707.712 us; speedup vs baseline: 1.8907x; 1.0326x over previous
//
#include <hip/hip_runtime.h>

#define NN 100000
#define NE 1600000
#define HID 64
#define TXT 384
#define BATCH 1024
#define NBUCK 391        // ceil(NN/256)
#define SBLK 256         // scatter/hist blocks
#define EPB ((NE + SBLK - 1) / SBLK)   // edges per block = 6250
#define LDA 40           // bf16 LDS row stride (80 B: 16B-aligned, 2-way banks)

typedef __attribute__((ext_vector_type(8))) short short8;
typedef __attribute__((ext_vector_type(4))) float float4v;

__device__ __forceinline__ ushort f2bf(float f) {
  unsigned u = __float_as_uint(f);
  unsigned r = (u + 0x7fffu + ((u >> 16) & 1u)) >> 16;  // round-to-nearest-even
  return (ushort)r;
}
__device__ __forceinline__ float bf2f(ushort u) {
  return __uint_as_float(((unsigned)u) << 16);
}

// ---- P1: per-(block,bucket) histogram matrix; no global atomics, no memset --
__global__ void k_hist2(const int* __restrict__ src, const int* __restrict__ dst,
                        int* __restrict__ cm_f, int* __restrict__ cm_r) {
  __shared__ int hf[NBUCK], hr[NBUCK];
  const int t = threadIdx.x, blk = blockIdx.x;
  for (int i = t; i < NBUCK; i += 256) { hf[i] = 0; hr[i] = 0; }
  __syncthreads();
  const int e0 = blk * EPB, e1 = min(NE, e0 + EPB);
  for (int e = e0 + t; e < e1; e += 256) {
    atomicAdd(&hf[dst[e] >> 8], 1);
    atomicAdd(&hr[src[e] >> 8], 1);
  }
  __syncthreads();
  for (int i = t; i < NBUCK; i += 256) {
    cm_f[i * SBLK + blk] = hf[i];
    cm_r[i * SBLK + blk] = hr[i];
  }
}

// ---- P2a: per-bucket exclusive scan over the 256 block-counts (in place) ----
__global__ void k_scan1(int* __restrict__ cm_f, int* __restrict__ cm_r,
                        int* __restrict__ btot) {
  __shared__ int tmp[256];
  const int t = threadIdx.x;
  int b = blockIdx.x;
  int* cm = (b < NBUCK) ? cm_f : cm_r;
  int bucket = (b < NBUCK) ? b : b - NBUCK;
  int* row = cm + bucket * SBLK;
  int v = row[t];
  tmp[t] = v; __syncthreads();
  for (int d = 1; d < 256; d <<= 1) {
    int s = tmp[t]; if (t >= d) s += tmp[t - d];
    __syncthreads(); tmp[t] = s; __syncthreads();
  }
  row[t] = tmp[t] - v;                 // exclusive prefix
  if (t == 255) btot[b] = tmp[t];      // bucket total
}

// ---- P2b: exclusive scan of bucket totals -> bucket bases -------------------
__global__ void k_scan2(const int* __restrict__ btot,
                        int* __restrict__ bbase_f, int* __restrict__ bbase_r) {
  __shared__ int tmp[512];
  const int t = threadIdx.x;
  int h = (t < NBUCK) ? btot[t] : 0;
  tmp[t] = h; __syncthreads();
  for (int d = 1; d < 512; d <<= 1) {
    int v = tmp[t]; if (t >= d) v += tmp[t - d];
    __syncthreads(); tmp[t] = v; __syncthreads();
  }
  if (t < NBUCK) bbase_f[t] = tmp[t] - h;
  __syncthreads();
  h = (t < NBUCK) ? btot[NBUCK + t] : 0;
  tmp[t] = h; __syncthreads();
  for (int d = 1; d < 512; d <<= 1) {
    int v = tmp[t]; if (t >= d) v += tmp[t - d];
    __syncthreads(); tmp[t] = v; __syncthreads();
  }
  if (t < NBUCK) bbase_r[t] = tmp[t] - h;
}

// ---- P3: scatter with LDS cursors only (zero global atomics) ----------------
__global__ void k_scatter2(const int* __restrict__ src, const int* __restrict__ dst,
                           const float* __restrict__ w,
                           const int* __restrict__ cm_f, const int* __restrict__ cm_r,
                           const int* __restrict__ bbase_f, const int* __restrict__ bbase_r,
                           int2* __restrict__ stg_f, int2* __restrict__ stg_r) {
  __shared__ int cur_f[NBUCK], cur_r[NBUCK];
  const int t = threadIdx.x, blk = blockIdx.x;
  for (int i = t; i < NBUCK; i += 256) {
    cur_f[i] = bbase_f[i] + cm_f[i * SBLK + blk];
    cur_r[i] = bbase_r[i] + cm_r[i * SBLK + blk];
  }
  __syncthreads();
  const int e0 = blk * EPB, e1 = min(NE, e0 + EPB);
  for (int e = e0 + t; e < e1; e += 256) {
    int s = src[e], d = dst[e];
    int wb = __float_as_int(w[e]);
    int p = atomicAdd(&cur_f[d >> 8], 1);
    stg_f[p] = make_int2(((d & 255) << 24) | s, wb);
    int q = atomicAdd(&cur_r[s >> 8], 1);
    stg_r[q] = make_int2(((s & 255) << 24) | d, wb);
  }
}

// ---- P4: per-bucket CSR finalize (one block per bucket) ---------------------
__global__ void p_build(const int2* __restrict__ stgf, const int* __restrict__ btotf,
                        const int* __restrict__ bbasef,
                        int* __restrict__ startf, int* __restrict__ cntf,
                        int2* __restrict__ cvf,
                        const int2* __restrict__ stgr, const int* __restrict__ btotr,
                        const int* __restrict__ bbaser,
                        int* __restrict__ startr, int* __restrict__ cntr,
                        int2* __restrict__ cvr) {
  int b = blockIdx.x;
  const int2* stg; const int* bcnt; const int* bbase;
  int* start; int* cnt; int2* cv;
  if (b < NBUCK) { stg = stgf; bcnt = btotf; bbase = bbasef; start = startf; cnt = cntf; cv = cvf; }
  else { b -= NBUCK; stg = stgr; bcnt = btotr; bbase = bbaser; start = startr; cnt = cntr; cv = cvr; }
  const int base = bbase[b];
  const int n = bcnt[b];
  const int t = threadIdx.x;
  __shared__ int hist[256], tmp[256], cur[256];
  hist[t] = 0;
  __syncthreads();
  for (int i = t; i < n; i += 256) {
    unsigned pk = (unsigned)stg[base + i].x;
    atomicAdd(&hist[pk >> 24], 1);
  }
  __syncthreads();
  const int h = hist[t];
  tmp[t] = h; __syncthreads();
  for (int d = 1; d < 256; d <<= 1) {
    int v = tmp[t]; if (t >= d) v += tmp[t - d];
    __syncthreads(); tmp[t] = v; __syncthreads();
  }
  const int excl = tmp[t] - h;
  const int node = (b << 8) + t;
  if (node < NN) { start[node] = base + excl; cnt[node] = h; }
  cur[t] = excl;
  __syncthreads();
  for (int i = t; i < n; i += 256) {
    int2 en = stg[base + i];
    unsigned d8 = ((unsigned)en.x) >> 24;
    int pos = atomicAdd(&cur[d8], 1);
    cv[base + pos] = make_int2(en.x & 0xFFFFFF, en.y);
  }
}

// ---- weighted-mean aggregation: 2 rows/wave, 32 lanes/row, bf16 reads -------
__global__ void k_gather(const ushort* __restrict__ xb,
                         const int* __restrict__ start, const int* __restrict__ cnt,
                         const int2* __restrict__ cv,
                         float* __restrict__ out) {
  int t = blockIdx.x * blockDim.x + threadIdx.x;
  int row = t >> 5;
  int l2 = (t & 31) * 2;
  if (row >= NN) return;
  int s = start[row];
  int c = cnt[row];
  int e = s + c;
  float ax = 0.f, ay = 0.f;
  int j = s;
  for (; j + 4 <= e; j += 4) {
    int2 e0 = cv[j], e1 = cv[j + 1], e2 = cv[j + 2], e3 = cv[j + 3];
    uint v0 = *(const uint*)(xb + (size_t)e0.x * 64 + l2);
    uint v1 = *(const uint*)(xb + (size_t)e1.x * 64 + l2);
    uint v2 = *(const uint*)(xb + (size_t)e2.x * 64 + l2);
    uint v3 = *(const uint*)(xb + (size_t)e3.x * 64 + l2);
    float w0 = __int_as_float(e0.y), w1 = __int_as_float(e1.y);
    float w2 = __int_as_float(e2.y), w3 = __int_as_float(e3.y);
    ax += w0 * bf2f((ushort)v0); ay += w0 * bf2f((ushort)(v0 >> 16));
    ax += w1 * bf2f((ushort)v1); ay += w1 * bf2f((ushort)(v1 >> 16));
    ax += w2 * bf2f((ushort)v2); ay += w2 * bf2f((ushort)(v2 >> 16));
    ax += w3 * bf2f((ushort)v3); ay += w3 * bf2f((ushort)(v3 >> 16));
  }
  for (; j < e; ++j) {
    int2 ee = cv[j];
    uint v = *(const uint*)(xb + (size_t)ee.x * 64 + l2);
    float ww = __int_as_float(ee.y);
    ax += ww * bf2f((ushort)v); ay += ww * bf2f((ushort)(v >> 16));
  }
  float inv = (c > 0) ? 1.0f / (float)c : 0.f;   // DGL mean; zero in-degree -> 0
  *(float2*)(out + (size_t)row * 64 + l2) = make_float2(ax * inv, ay * inv);
}

// ---- encoder: MFMA bf16 GEMM [NN,384]@[384,64]+b -> x fp32 (+ bf16 mirror) --
// 128 rows/block (782 blocks), fp32->bf16 conversion fused into LDS staging.
// Wave tile 32x64 = 2 Mtiles x 4 Ntiles of 16x16x32 MFMA, fp32 accumulate.
__launch_bounds__(256)
__global__ void k_enc(const float* __restrict__ T, const float* __restrict__ W,
                      const float* __restrict__ bias, float* __restrict__ x,
                      ushort* __restrict__ xb) {
  __shared__ short As[128 * LDA];   // A tile, [row][k] bf16
  __shared__ short Bt[64 * LDA];    // B tile transposed, [n][k] bf16
  const int tid = threadIdx.x;
  const int row0 = blockIdx.x * 128;
  const int wave = tid >> 6, lane = tid & 63;
  const int quad = lane >> 4, lr = lane & 15;
  float4v acc[2][4] = {};

  const int srow = tid >> 1;            // 0..127 : A staging row
  const int shalf = (tid & 1) * 16;     // 0 or 16: 16-float half of the 32-k chunk
  const int grow = min(row0 + srow, NN - 1);
  const float* tp = T + (size_t)grow * TXT + shalf;
  const int bn = tid & 63;              // B staging: n
  const int bk = (tid >> 6) * 8;        // B staging: k-group (wave w -> k 8w..8w+7)

  #pragma unroll 1
  for (int ch = 0; ch < 12; ++ch) {
    const int kc = ch * 32;
    // A: 128x32 fp32 -> bf16 LDS (each thread: 16 floats -> two short8 stores)
    float4 a0 = *(const float4*)(tp + kc);
    float4 a1 = *(const float4*)(tp + kc + 4);
    float4 a2 = *(const float4*)(tp + kc + 8);
    float4 a3 = *(const float4*)(tp + kc + 12);
    short8 s0, s1;
    s0[0] = (short)f2bf(a0.x); s0[1] = (short)f2bf(a0.y);
    s0[2] = (short)f2bf(a0.z); s0[3] = (short)f2bf(a0.w);
    s0[4] = (short)f2bf(a1.x); s0[5] = (short)f2bf(a1.y);
    s0[6] = (short)f2bf(a1.z); s0[7] = (short)f2bf(a1.w);
    s1[0] = (short)f2bf(a2.x); s1[1] = (short)f2bf(a2.y);
    s1[2] = (short)f2bf(a2.z); s1[3] = (short)f2bf(a2.w);
    s1[4] = (short)f2bf(a3.x); s1[5] = (short)f2bf(a3.y);
    s1[6] = (short)f2bf(a3.z); s1[7] = (short)f2bf(a3.w);
    *(short8*)&As[srow * LDA + shalf] = s0;
    *(short8*)&As[srow * LDA + shalf + 8] = s1;
    // B: 32x64 fp32 -> Bt[n][k] bf16 (wave w stages k = 8w..8w+7, coalesced reads)
    #pragma unroll
    for (int j = 0; j < 8; ++j)
      Bt[bn * LDA + bk + j] = (short)f2bf(W[(kc + bk + j) * 64 + bn]);
    __syncthreads();
    // MFMA: wave covers rows wave*32 .. +32
    const int ar = wave * 32 + lr;
    short8 af0 = *(const short8*)&As[ar * LDA + quad * 8];
    short8 af1 = *(const short8*)&As[(ar + 16) * LDA + quad * 8];
    #pragma unroll
    for (int nt = 0; nt < 4; ++nt) {
      short8 bfrag = *(const short8*)&Bt[(nt * 16 + lr) * LDA + quad * 8];
      acc[0][nt] = __builtin_amdgcn_mfma_f32_16x16x32_bf16(af0, bfrag, acc[0][nt], 0, 0, 0);
      acc[1][nt] = __builtin_amdgcn_mfma_f32_16x16x32_bf16(af1, bfrag, acc[1][nt], 0, 0, 0);
    }
    __syncthreads();
  }
  // epilogue: D[row = quad*4+r (+16*mt, +32*wave), col = nt*16+lr]
  #pragma unroll
  for (int nt = 0; nt < 4; ++nt) {
    const int col = nt * 16 + lr;
    const float bcol = bias[col];
    #pragma unroll
    for (int mt = 0; mt < 2; ++mt) {
      #pragma unroll
      for (int r = 0; r < 4; ++r) {
        const int row = row0 + wave * 32 + mt * 16 + quad * 4 + r;
        if (row < NN) {
          float v = acc[mt][nt][r] + bcol;
          x[(size_t)row * 64 + col] = v;
          xb[(size_t)row * 64 + col] = f2bf(v);
        }
      }
    }
  }
}

// ---- per-direction combine GEMM: [NN,128]@[128,64] --------------------------
// mode 0: n := relu(acc + bias)   mode 1: x += yrel + relu(acc + bias); xb=bf16(x)
__launch_bounds__(256)
__global__ void k_gemm(const float* __restrict__ A1, float* __restrict__ n,
                       const float* __restrict__ yrel,
                       const float* __restrict__ B1, const float* __restrict__ B2,
                       const float* __restrict__ bias,
                       float* __restrict__ x, ushort* __restrict__ xb, int mode) {
  __shared__ float As[32][256];
  __shared__ float Bs[32][64];
  const int tid = threadIdx.x;
  const int row0 = blockIdx.x * 256;
  const int rg = tid >> 3, cg = tid & 7;
  float acc[8][8] = {};
  #pragma unroll 1
  for (int ch = 0; ch < 4; ++ch) {
    const float* Asrc = (ch < 2) ? A1 : n;
    const float* Bsrc = (ch < 2) ? B1 : B2;
    const int kc = (ch & 1) * 32;
    const int arow = row0 + tid;
    if (arow < NN) {
      const float* p = Asrc + (size_t)arow * 64 + kc;
      #pragma unroll
      for (int j = 0; j < 32; j += 4) {
        float4 v = *(const float4*)(p + j);
        As[j + 0][tid] = v.x; As[j + 1][tid] = v.y;
        As[j + 2][tid] = v.z; As[j + 3][tid] = v.w;
      }
    } else {
      #pragma unroll
      for (int j = 0; j < 32; ++j) As[j][tid] = 0.f;
    }
    {
      const int i = tid * 8, k = i >> 6, c = i & 63;
      float4 v0 = *(const float4*)(Bsrc + (kc + k) * 64 + c);
      float4 v1 = *(const float4*)(Bsrc + (kc + k) * 64 + c + 4);
      *(float4*)&Bs[k][c] = v0; *(float4*)&Bs[k][c + 4] = v1;
    }
    __syncthreads();
    #pragma unroll 4
    for (int k = 0; k < 32; ++k) {
      float4 a0 = *(const float4*)&As[k][rg * 8];
      float4 a1 = *(const float4*)&As[k][rg * 8 + 4];
      float4 b0 = *(const float4*)&Bs[k][cg * 8];
      float4 b1 = *(const float4*)&Bs[k][cg * 8 + 4];
      const float a[8] = {a0.x, a0.y, a0.z, a0.w, a1.x, a1.y, a1.z, a1.w};
      const float b[8] = {b0.x, b0.y, b0.z, b0.w, b1.x, b1.y, b1.z, b1.w};
      #pragma unroll
      for (int i = 0; i < 8; ++i)
        #pragma unroll
        for (int jj = 0; jj < 8; ++jj)
          acc[i][jj] = fmaf(a[i], b[jj], acc[i][jj]);
    }
    __syncthreads();
  }
  #pragma unroll
  for (int i = 0; i < 8; ++i) {
    const int row = row0 + rg * 8 + i;
    if (row >= NN) continue;
    const int c0 = cg * 8;
    float vv[8];
    #pragma unroll
    for (int j = 0; j < 8; ++j) vv[j] = acc[i][j] + bias[c0 + j];
    if (mode == 0) {
      float* np = n + (size_t)row * 64 + c0;
      *(float4*)np = make_float4(fmaxf(vv[0], 0.f), fmaxf(vv[1], 0.f),
                                 fmaxf(vv[2], 0.f), fmaxf(vv[3], 0.f));
      *(float4*)(np + 4) = make_float4(fmaxf(vv[4], 0.f), fmaxf(vv[5], 0.f),
                                       fmaxf(vv[6], 0.f), fmaxf(vv[7], 0.f));
    } else {
      size_t base = (size_t)row * 64 + c0;
      float4 nf0 = *(const float4*)(yrel + base);
      float4 nf1 = *(const float4*)(yrel + base + 4);
      float4 x0 = *(const float4*)(x + base);
      float4 x1 = *(const float4*)(x + base + 4);
      float nv[8] = {nf0.x, nf0.y, nf0.z, nf0.w, nf1.x, nf1.y, nf1.z, nf1.w};
      float xv[8] = {x0.x, x0.y, x0.z, x0.w, x1.x, x1.y, x1.z, x1.w};
      float o[8];
      #pragma unroll
      for (int j = 0; j < 8; ++j) o[j] = xv[j] + nv[j] + fmaxf(vv[j], 0.f);
      *(float4*)(x + base) = make_float4(o[0], o[1], o[2], o[3]);
      *(float4*)(x + base + 4) = make_float4(o[4], o[5], o[6], o[7]);
      uint p4[4];
      #pragma unroll
      for (int j = 0; j < 4; ++j)
        p4[j] = (uint)f2bf(o[2 * j]) | ((uint)f2bf(o[2 * j + 1]) << 16);
      *(uint4*)(xb + base) = make_uint4(p4[0], p4[1], p4[2], p4[3]);
    }
  }
}

// ---- output gather + L2 normalize -------------------------------------------
__global__ void k_out(const float* __restrict__ x, const int* __restrict__ ids,
                      float* __restrict__ out) {
  int b = (blockIdx.x * blockDim.x + threadIdx.x) >> 6;
  int lane = threadIdx.x & 63;
  if (b >= BATCH) return;
  int row = ids[b];
  float v = x[(size_t)row * 64 + lane];
  float s = v * v;
  #pragma unroll
  for (int m = 1; m < 64; m <<= 1) s += __shfl_xor(s, m);
  out[b * 64 + lane] = v / sqrtf(s);
}

extern "C" void kernel_launch(void* const* d_in, const int* in_sizes, int n_in,
                              void* d_out, int out_size, void* d_ws, size_t ws_size,
                              hipStream_t stream) {
  const float* text = (const float*)d_in[0];
  const float* wts  = (const float*)d_in[1];
  const float* Wenc = (const float*)d_in[2];
  const float* benc = (const float*)d_in[3];
  const float* Wsf  = (const float*)d_in[4];
  const float* Wnf  = (const float*)d_in[5];
  const float* bf   = (const float*)d_in[6];
  const float* Wsr  = (const float*)d_in[7];
  const float* Wnr  = (const float*)d_in[8];
  const float* br   = (const float*)d_in[9];
  const int*   src  = (const int*)d_in[10];
  const int*   dst  = (const int*)d_in[11];
  const int*   ids  = (const int*)d_in[12];
  float* out = (float*)d_out;

  char* ws = (char*)d_ws;
  size_t o = 0;
  auto alloc = [&](size_t f32elems) {
    void* p = ws + o;
    o += f32elems * 4;
    o = (o + 255) & ~(size_t)255;
    return p;
  };
  float*  x   = (float*)alloc((size_t)NN * 64);
  float*  nf  = (float*)alloc((size_t)NN * 64);   // aliased as stage_f
  float*  nr  = (float*)alloc((size_t)NN * 64);   // aliased as stage_r
  ushort* xb  = (ushort*)alloc((size_t)NN * 32);  // bf16 mirror of x
  int2*   cvf = (int2*)alloc((size_t)NE * 2);     // final CSR (col, weight)
  int2*   cvr = (int2*)alloc((size_t)NE * 2);
  int* cm_f    = (int*)alloc((size_t)NBUCK * SBLK);  // count/prefix matrix
  int* cm_r    = (int*)alloc((size_t)NBUCK * SBLK);
  int* btot    = (int*)alloc(2 * NBUCK);
  int* bbase_f = (int*)alloc(NBUCK);
  int* bbase_r = (int*)alloc(NBUCK);
  int* startf  = (int*)alloc(NN);
  int* cntf    = (int*)alloc(NN);
  int* startr  = (int*)alloc(NN);
  int* cntr    = (int*)alloc(NN);

  int2* stg_f = (int2*)nf;   // staging dead before first gather writes nf
  int2* stg_r = (int2*)nr;

  const int VB = (NN + 255) / 256;
  const int EB2 = (NN + 127) / 128;   // 782 blocks for MFMA encoder

  k_hist2<<<SBLK, 256, 0, stream>>>(src, dst, cm_f, cm_r);
  k_scan1<<<2 * NBUCK, 256, 0, stream>>>(cm_f, cm_r, btot);
  k_scan2<<<1, 512, 0, stream>>>(btot, bbase_f, bbase_r);
  k_scatter2<<<SBLK, 256, 0, stream>>>(src, dst, wts, cm_f, cm_r,
                                       bbase_f, bbase_r, stg_f, stg_r);
  p_build<<<2 * NBUCK, 256, 0, stream>>>(stg_f, btot, bbase_f, startf, cntf, cvf,
                                         stg_r, btot + NBUCK, bbase_r, startr, cntr, cvr);
  k_enc<<<EB2, 256, 0, stream>>>(text, Wenc, benc, x, xb);

  const int GB = ((size_t)NN * 32 + 255) / 256;  // 2 rows per wave
  for (int l = 0; l < 2; ++l) {
    const float* Wsf_l = Wsf + l * HID * HID;
    const float* Wnf_l = Wnf + l * HID * HID;
    const float* Wsr_l = Wsr + l * HID * HID;
    const float* Wnr_l = Wnr + l * HID * HID;
    const float* bf_l  = bf + l * HID;
    const float* br_l  = br + l * HID;
    k_gather<<<GB, 256, 0, stream>>>(xb, startf, cntf, cvf, nf);
    k_gather<<<GB, 256, 0, stream>>>(xb, startr, cntr, cvr, nr);
    // mode 0: nf := relu(y_f)
    k_gemm<<<VB, 256, 0, stream>>>(x, nf, nf, Wsf_l, Wnf_l, bf_l, x, xb, 0);
    // mode 1: x += nf (=relu(y_f)) + relu(y_r)
    k_gemm<<<VB, 256, 0, stream>>>(x, nr, nf, Wsr_l, Wnr_l, br_l, x, xb, 1);
  }
  k_out<<<(BATCH * 64) / 256, 256, 0, stream>>>(x, ids, out);
}

// Round 7
// 615.250 us; speedup vs baseline: 2.1748x; 1.1503x over previous
//
#include <hip/hip_runtime.h>

#define NN 100000
#define NE 1600000
#define HID 64
#define TXT 384
#define BATCH 1024
#define NBUCK 391        // ceil(NN/256)
#define SBLK 256         // scatter/hist blocks
#define EPB ((NE + SBLK - 1) / SBLK)   // edges per block = 6250
#define LDA 40           // k_enc A-tile bf16 stride (80 B)
#define LDB 392          // k_enc full-K B-tile bf16 stride (784 B)
#define LDK2 72          // k_layer bf16 stride (144 B)

typedef __attribute__((ext_vector_type(8))) short short8;
typedef __attribute__((ext_vector_type(4))) float float4v;

__device__ __forceinline__ ushort f2bf(float f) {
  unsigned u = __float_as_uint(f);
  unsigned r = (u + 0x7fffu + ((u >> 16) & 1u)) >> 16;  // round-to-nearest-even
  return (ushort)r;
}
__device__ __forceinline__ float bf2f(ushort u) {
  return __uint_as_float(((unsigned)u) << 16);
}

// ---- P1: per-(block,bucket) histogram matrix --------------------------------
__global__ void k_hist2(const int* __restrict__ src, const int* __restrict__ dst,
                        int* __restrict__ cm_f, int* __restrict__ cm_r) {
  __shared__ int hf[NBUCK], hr[NBUCK];
  const int t = threadIdx.x, blk = blockIdx.x;
  for (int i = t; i < NBUCK; i += 256) { hf[i] = 0; hr[i] = 0; }
  __syncthreads();
  const int e0 = blk * EPB, e1 = min(NE, e0 + EPB);
  for (int e = e0 + t; e < e1; e += 256) {
    atomicAdd(&hf[dst[e] >> 8], 1);
    atomicAdd(&hr[src[e] >> 8], 1);
  }
  __syncthreads();
  for (int i = t; i < NBUCK; i += 256) {
    cm_f[i * SBLK + blk] = hf[i];
    cm_r[i * SBLK + blk] = hr[i];
  }
}

// ---- P2a: per-bucket exclusive scan over the 256 block-counts ---------------
__global__ void k_scan1(int* __restrict__ cm_f, int* __restrict__ cm_r,
                        int* __restrict__ btot) {
  __shared__ int tmp[256];
  const int t = threadIdx.x;
  int b = blockIdx.x;
  int* cm = (b < NBUCK) ? cm_f : cm_r;
  int bucket = (b < NBUCK) ? b : b - NBUCK;
  int* row = cm + bucket * SBLK;
  int v = row[t];
  tmp[t] = v; __syncthreads();
  for (int d = 1; d < 256; d <<= 1) {
    int s = tmp[t]; if (t >= d) s += tmp[t - d];
    __syncthreads(); tmp[t] = s; __syncthreads();
  }
  row[t] = tmp[t] - v;
  if (t == 255) btot[b] = tmp[t];
}

// ---- P2b: exclusive scan of bucket totals -> bucket bases -------------------
__global__ void k_scan2(const int* __restrict__ btot,
                        int* __restrict__ bbase_f, int* __restrict__ bbase_r) {
  __shared__ int tmp[512];
  const int t = threadIdx.x;
  int h = (t < NBUCK) ? btot[t] : 0;
  tmp[t] = h; __syncthreads();
  for (int d = 1; d < 512; d <<= 1) {
    int v = tmp[t]; if (t >= d) v += tmp[t - d];
    __syncthreads(); tmp[t] = v; __syncthreads();
  }
  if (t < NBUCK) bbase_f[t] = tmp[t] - h;
  __syncthreads();
  h = (t < NBUCK) ? btot[NBUCK + t] : 0;
  tmp[t] = h; __syncthreads();
  for (int d = 1; d < 512; d <<= 1) {
    int v = tmp[t]; if (t >= d) v += tmp[t - d];
    __syncthreads(); tmp[t] = v; __syncthreads();
  }
  if (t < NBUCK) bbase_r[t] = tmp[t] - h;
}

// ---- P3: scatter with LDS cursors only (zero global atomics) ----------------
__global__ void k_scatter2(const int* __restrict__ src, const int* __restrict__ dst,
                           const float* __restrict__ w,
                           const int* __restrict__ cm_f, const int* __restrict__ cm_r,
                           const int* __restrict__ bbase_f, const int* __restrict__ bbase_r,
                           int2* __restrict__ stg_f, int2* __restrict__ stg_r) {
  __shared__ int cur_f[NBUCK], cur_r[NBUCK];
  const int t = threadIdx.x, blk = blockIdx.x;
  for (int i = t; i < NBUCK; i += 256) {
    cur_f[i] = bbase_f[i] + cm_f[i * SBLK + blk];
    cur_r[i] = bbase_r[i] + cm_r[i * SBLK + blk];
  }
  __syncthreads();
  const int e0 = blk * EPB, e1 = min(NE, e0 + EPB);
  for (int e = e0 + t; e < e1; e += 256) {
    int s = src[e], d = dst[e];
    int wb = __float_as_int(w[e]);
    int p = atomicAdd(&cur_f[d >> 8], 1);
    stg_f[p] = make_int2(((d & 255) << 24) | s, wb);
    int q = atomicAdd(&cur_r[s >> 8], 1);
    stg_r[q] = make_int2(((s & 255) << 24) | d, wb);
  }
}

// ---- P4: per-bucket CSR finalize --------------------------------------------
__global__ void p_build(const int2* __restrict__ stgf, const int* __restrict__ btotf,
                        const int* __restrict__ bbasef,
                        int* __restrict__ startf, int* __restrict__ cntf,
                        int2* __restrict__ cvf,
                        const int2* __restrict__ stgr, const int* __restrict__ btotr,
                        const int* __restrict__ bbaser,
                        int* __restrict__ startr, int* __restrict__ cntr,
                        int2* __restrict__ cvr) {
  int b = blockIdx.x;
  const int2* stg; const int* bcnt; const int* bbase;
  int* start; int* cnt; int2* cv;
  if (b < NBUCK) { stg = stgf; bcnt = btotf; bbase = bbasef; start = startf; cnt = cntf; cv = cvf; }
  else { b -= NBUCK; stg = stgr; bcnt = btotr; bbase = bbaser; start = startr; cnt = cntr; cv = cvr; }
  const int base = bbase[b];
  const int n = bcnt[b];
  const int t = threadIdx.x;
  __shared__ int hist[256], tmp[256], cur[256];
  hist[t] = 0;
  __syncthreads();
  for (int i = t; i < n; i += 256) {
    unsigned pk = (unsigned)stg[base + i].x;
    atomicAdd(&hist[pk >> 24], 1);
  }
  __syncthreads();
  const int h = hist[t];
  tmp[t] = h; __syncthreads();
  for (int d = 1; d < 256; d <<= 1) {
    int v = tmp[t]; if (t >= d) v += tmp[t - d];
    __syncthreads(); tmp[t] = v; __syncthreads();
  }
  const int excl = tmp[t] - h;
  const int node = (b << 8) + t;
  if (node < NN) { start[node] = base + excl; cnt[node] = h; }
  cur[t] = excl;
  __syncthreads();
  for (int i = t; i < n; i += 256) {
    int2 en = stg[base + i];
    unsigned d8 = ((unsigned)en.x) >> 24;
    int pos = atomicAdd(&cur[d8], 1);
    cv[base + pos] = make_int2(en.x & 0xFFFFFF, en.y);
  }
}

// ---- weighted-mean aggregation, BOTH directions in one dispatch -------------
// 2 rows/wave, 32 lanes/row; bf16 in, bf16 out (packed uint writes)
__global__ void k_gather2(const ushort* __restrict__ xb,
                          const int* __restrict__ startf, const int* __restrict__ cntf,
                          const int2* __restrict__ cvf, ushort* __restrict__ nbf,
                          const int* __restrict__ startr, const int* __restrict__ cntr,
                          const int2* __restrict__ cvr, ushort* __restrict__ nbr) {
  const int GBc = ((NN * 32) + 255) / 256;
  int b = blockIdx.x;
  const int* start; const int* cnt; const int2* cv; ushort* outp;
  if (b < GBc) { start = startf; cnt = cntf; cv = cvf; outp = nbf; }
  else { b -= GBc; start = startr; cnt = cntr; cv = cvr; outp = nbr; }
  int t = b * 256 + threadIdx.x;
  int row = t >> 5;
  int l2 = (t & 31) * 2;
  if (row >= NN) return;
  int s = start[row];
  int c = cnt[row];
  int e = s + c;
  float ax = 0.f, ay = 0.f;
  int j = s;
  for (; j + 4 <= e; j += 4) {
    int2 e0 = cv[j], e1 = cv[j + 1], e2 = cv[j + 2], e3 = cv[j + 3];
    uint v0 = *(const uint*)(xb + (size_t)e0.x * 64 + l2);
    uint v1 = *(const uint*)(xb + (size_t)e1.x * 64 + l2);
    uint v2 = *(const uint*)(xb + (size_t)e2.x * 64 + l2);
    uint v3 = *(const uint*)(xb + (size_t)e3.x * 64 + l2);
    float w0 = __int_as_float(e0.y), w1 = __int_as_float(e1.y);
    float w2 = __int_as_float(e2.y), w3 = __int_as_float(e3.y);
    ax += w0 * bf2f((ushort)v0); ay += w0 * bf2f((ushort)(v0 >> 16));
    ax += w1 * bf2f((ushort)v1); ay += w1 * bf2f((ushort)(v1 >> 16));
    ax += w2 * bf2f((ushort)v2); ay += w2 * bf2f((ushort)(v2 >> 16));
    ax += w3 * bf2f((ushort)v3); ay += w3 * bf2f((ushort)(v3 >> 16));
  }
  for (; j < e; ++j) {
    int2 ee = cv[j];
    uint v = *(const uint*)(xb + (size_t)ee.x * 64 + l2);
    float ww = __int_as_float(ee.y);
    ax += ww * bf2f((ushort)v); ay += ww * bf2f((ushort)(v >> 16));
  }
  float inv = (c > 0) ? 1.0f / (float)c : 0.f;   // DGL mean; zero in-degree -> 0
  uint pv = (uint)f2bf(ax * inv) | ((uint)f2bf(ay * inv) << 16);
  *(uint*)(outp + (size_t)row * 64 + l2) = pv;
}

// ---- encoder: MFMA bf16 GEMM, W staged once, A register-prefetch pipeline ---
__launch_bounds__(256)
__global__ void k_enc(const float* __restrict__ T, const float* __restrict__ W,
                      const float* __restrict__ bias, float* __restrict__ x,
                      ushort* __restrict__ xb) {
  __shared__ short Bt[64 * LDB];    // full-K B, [n][k] bf16 (50 KB)
  __shared__ short As[128 * LDA];   // one 128x32 A chunk (10 KB)
  const int tid = threadIdx.x;
  const int row0 = blockIdx.x * 128;
  const int wave = tid >> 6, lane = tid & 63;
  const int quad = lane >> 4, lr = lane & 15;
  float4v acc[2][4] = {};

  // stage ALL of W once: 384x64 fp32 -> bf16 [n][k]
  #pragma unroll 4
  for (int j = 0; j < 96; ++j) {
    int idx = j * 256 + tid;
    int k = idx >> 6, n = idx & 63;
    Bt[n * LDB + k] = (short)f2bf(W[idx]);
  }

  const int srow = tid >> 1;
  const int shalf = (tid & 1) * 16;
  const int grow = min(row0 + srow, NN - 1);
  const float* tp = T + (size_t)grow * TXT + shalf;

  // preload chunk 0, store, preload chunk 1
  float4 pa0 = *(const float4*)(tp + 0);
  float4 pa1 = *(const float4*)(tp + 4);
  float4 pa2 = *(const float4*)(tp + 8);
  float4 pa3 = *(const float4*)(tp + 12);
  {
    short8 s0, s1;
    s0[0]=(short)f2bf(pa0.x); s0[1]=(short)f2bf(pa0.y); s0[2]=(short)f2bf(pa0.z); s0[3]=(short)f2bf(pa0.w);
    s0[4]=(short)f2bf(pa1.x); s0[5]=(short)f2bf(pa1.y); s0[6]=(short)f2bf(pa1.z); s0[7]=(short)f2bf(pa1.w);
    s1[0]=(short)f2bf(pa2.x); s1[1]=(short)f2bf(pa2.y); s1[2]=(short)f2bf(pa2.z); s1[3]=(short)f2bf(pa2.w);
    s1[4]=(short)f2bf(pa3.x); s1[5]=(short)f2bf(pa3.y); s1[6]=(short)f2bf(pa3.z); s1[7]=(short)f2bf(pa3.w);
    *(short8*)&As[srow * LDA + shalf] = s0;
    *(short8*)&As[srow * LDA + shalf + 8] = s1;
  }
  pa0 = *(const float4*)(tp + 32);
  pa1 = *(const float4*)(tp + 36);
  pa2 = *(const float4*)(tp + 40);
  pa3 = *(const float4*)(tp + 44);
  __syncthreads();

  #pragma unroll 1
  for (int ch = 0; ch < 12; ++ch) {
    // MFMA on current chunk
    const int ar = wave * 32 + lr;
    short8 af0 = *(const short8*)&As[ar * LDA + quad * 8];
    short8 af1 = *(const short8*)&As[(ar + 16) * LDA + quad * 8];
    #pragma unroll
    for (int nt = 0; nt < 4; ++nt) {
      short8 bfrag = *(const short8*)&Bt[(nt * 16 + lr) * LDB + ch * 32 + quad * 8];
      acc[0][nt] = __builtin_amdgcn_mfma_f32_16x16x32_bf16(af0, bfrag, acc[0][nt], 0, 0, 0);
      acc[1][nt] = __builtin_amdgcn_mfma_f32_16x16x32_bf16(af1, bfrag, acc[1][nt], 0, 0, 0);
    }
    __syncthreads();                         // all reads of As done
    if (ch < 11) {
      short8 s0, s1;
      s0[0]=(short)f2bf(pa0.x); s0[1]=(short)f2bf(pa0.y); s0[2]=(short)f2bf(pa0.z); s0[3]=(short)f2bf(pa0.w);
      s0[4]=(short)f2bf(pa1.x); s0[5]=(short)f2bf(pa1.y); s0[6]=(short)f2bf(pa1.z); s0[7]=(short)f2bf(pa1.w);
      s1[0]=(short)f2bf(pa2.x); s1[1]=(short)f2bf(pa2.y); s1[2]=(short)f2bf(pa2.z); s1[3]=(short)f2bf(pa2.w);
      s1[4]=(short)f2bf(pa3.x); s1[5]=(short)f2bf(pa3.y); s1[6]=(short)f2bf(pa3.z); s1[7]=(short)f2bf(pa3.w);
      *(short8*)&As[srow * LDA + shalf] = s0;
      *(short8*)&As[srow * LDA + shalf + 8] = s1;
      if (ch + 2 < 12) {
        const int kc = (ch + 2) * 32;
        pa0 = *(const float4*)(tp + kc);
        pa1 = *(const float4*)(tp + kc + 4);
        pa2 = *(const float4*)(tp + kc + 8);
        pa3 = *(const float4*)(tp + kc + 12);
      }
      __syncthreads();                       // new As visible
    }
  }
  // epilogue
  #pragma unroll
  for (int nt = 0; nt < 4; ++nt) {
    const int col = nt * 16 + lr;
    const float bcol = bias[col];
    #pragma unroll
    for (int mt = 0; mt < 2; ++mt) {
      #pragma unroll
      for (int r = 0; r < 4; ++r) {
        const int row = row0 + wave * 32 + mt * 16 + quad * 4 + r;
        if (row < NN) {
          float v = acc[mt][nt][r] + bcol;
          x[(size_t)row * 64 + col] = v;
          xb[(size_t)row * 64 + col] = f2bf(v);
        }
      }
    }
  }
}

// ---- fused per-layer combine: x += relu(xb@Wsf + nbf@Wnf + bf)
//                                  + relu(xb@Wsr + nbr@Wnr + br);  xb = bf16(x)
__launch_bounds__(256)
__global__ void k_layer(const ushort* __restrict__ xbin,
                        const ushort* __restrict__ nbf, const ushort* __restrict__ nbr,
                        const float* __restrict__ Wsf, const float* __restrict__ Wnf,
                        const float* __restrict__ bfv,
                        const float* __restrict__ Wsr, const float* __restrict__ Wnr,
                        const float* __restrict__ brv,
                        float* __restrict__ x, ushort* __restrict__ xb) {
  __shared__ short B4[4 * 64 * LDK2];   // Wsf, Wsr, Wnf, Wnr bf16 [n][k] (36 KB)
  __shared__ short As[128 * LDK2];      // one bf16 A tile (18 KB)
  const int tid = threadIdx.x;
  const int row0 = blockIdx.x * 128;
  const int wave = tid >> 6, lane = tid & 63;
  const int quad = lane >> 4, lr = lane & 15;

  // stage 4 weight matrices
  {
    const float* wm0 = Wsf; const float* wm1 = Wsr;
    const float* wm2 = Wnf; const float* wm3 = Wnr;
    #pragma unroll
    for (int j = 0; j < 16; ++j) {
      int idx = j * 256 + tid;
      int k = idx >> 6, n = idx & 63;
      B4[0 * 64 * LDK2 + n * LDK2 + k] = (short)f2bf(wm0[idx]);
      B4[1 * 64 * LDK2 + n * LDK2 + k] = (short)f2bf(wm1[idx]);
      B4[2 * 64 * LDK2 + n * LDK2 + k] = (short)f2bf(wm2[idx]);
      B4[3 * 64 * LDK2 + n * LDK2 + k] = (short)f2bf(wm3[idx]);
    }
  }
  // stage A = xb tile; prefetch nbf into regs
  const int srow = tid >> 1, half = (tid & 1) * 32;
  const int grow = min(row0 + srow, NN - 1);
  {
    const uint4* s = (const uint4*)(xbin + (size_t)grow * 64 + half);
    uint4* d = (uint4*)&As[srow * LDK2 + half];
    d[0] = s[0]; d[1] = s[1]; d[2] = s[2]; d[3] = s[3];
  }
  const uint4* pf = (const uint4*)(nbf + (size_t)grow * 64 + half);
  uint4 p0 = pf[0], p1 = pf[1], p2 = pf[2], p3 = pf[3];
  __syncthreads();

  float4v accf[2][4] = {}, accr[2][4] = {};
  // phase 1: xb x {Wsf, Wsr}
  #pragma unroll
  for (int kk = 0; kk < 64; kk += 32) {
    short8 a0 = *(const short8*)&As[(wave * 32 + lr) * LDK2 + kk + quad * 8];
    short8 a1 = *(const short8*)&As[(wave * 32 + 16 + lr) * LDK2 + kk + quad * 8];
    #pragma unroll
    for (int nt = 0; nt < 4; ++nt) {
      short8 bs = *(const short8*)&B4[0 * 64 * LDK2 + (nt * 16 + lr) * LDK2 + kk + quad * 8];
      accf[0][nt] = __builtin_amdgcn_mfma_f32_16x16x32_bf16(a0, bs, accf[0][nt], 0, 0, 0);
      accf[1][nt] = __builtin_amdgcn_mfma_f32_16x16x32_bf16(a1, bs, accf[1][nt], 0, 0, 0);
      short8 bq = *(const short8*)&B4[1 * 64 * LDK2 + (nt * 16 + lr) * LDK2 + kk + quad * 8];
      accr[0][nt] = __builtin_amdgcn_mfma_f32_16x16x32_bf16(a0, bq, accr[0][nt], 0, 0, 0);
      accr[1][nt] = __builtin_amdgcn_mfma_f32_16x16x32_bf16(a1, bq, accr[1][nt], 0, 0, 0);
    }
  }
  __syncthreads();
  // store nbf tile; prefetch nbr
  { uint4* d = (uint4*)&As[srow * LDK2 + half]; d[0] = p0; d[1] = p1; d[2] = p2; d[3] = p3; }
  {
    const uint4* pr = (const uint4*)(nbr + (size_t)grow * 64 + half);
    p0 = pr[0]; p1 = pr[1]; p2 = pr[2]; p3 = pr[3];
  }
  __syncthreads();
  // phase 2: nbf x Wnf -> accf
  #pragma unroll
  for (int kk = 0; kk < 64; kk += 32) {
    short8 a0 = *(const short8*)&As[(wave * 32 + lr) * LDK2 + kk + quad * 8];
    short8 a1 = *(const short8*)&As[(wave * 32 + 16 + lr) * LDK2 + kk + quad * 8];
    #pragma unroll
    for (int nt = 0; nt < 4; ++nt) {
      short8 bs = *(const short8*)&B4[2 * 64 * LDK2 + (nt * 16 + lr) * LDK2 + kk + quad * 8];
      accf[0][nt] = __builtin_amdgcn_mfma_f32_16x16x32_bf16(a0, bs, accf[0][nt], 0, 0, 0);
      accf[1][nt] = __builtin_amdgcn_mfma_f32_16x16x32_bf16(a1, bs, accf[1][nt], 0, 0, 0);
    }
  }
  __syncthreads();
  // store nbr tile
  { uint4* d = (uint4*)&As[srow * LDK2 + half]; d[0] = p0; d[1] = p1; d[2] = p2; d[3] = p3; }
  __syncthreads();
  // phase 3: nbr x Wnr -> accr
  #pragma unroll
  for (int kk = 0; kk < 64; kk += 32) {
    short8 a0 = *(const short8*)&As[(wave * 32 + lr) * LDK2 + kk + quad * 8];
    short8 a1 = *(const short8*)&As[(wave * 32 + 16 + lr) * LDK2 + kk + quad * 8];
    #pragma unroll
    for (int nt = 0; nt < 4; ++nt) {
      short8 bs = *(const short8*)&B4[3 * 64 * LDK2 + (nt * 16 + lr) * LDK2 + kk + quad * 8];
      accr[0][nt] = __builtin_amdgcn_mfma_f32_16x16x32_bf16(a0, bs, accr[0][nt], 0, 0, 0);
      accr[1][nt] = __builtin_amdgcn_mfma_f32_16x16x32_bf16(a1, bs, accr[1][nt], 0, 0, 0);
    }
  }
  // epilogue: skip connection in fp32
  #pragma unroll
  for (int nt = 0; nt < 4; ++nt) {
    const int col = nt * 16 + lr;
    const float bf_c = bfv[col], br_c = brv[col];
    #pragma unroll
    for (int mt = 0; mt < 2; ++mt) {
      #pragma unroll
      for (int r = 0; r < 4; ++r) {
        const int row = row0 + wave * 32 + mt * 16 + quad * 4 + r;
        if (row < NN) {
          size_t idx = (size_t)row * 64 + col;
          float v = x[idx] + fmaxf(accf[mt][nt][r] + bf_c, 0.f)
                           + fmaxf(accr[mt][nt][r] + br_c, 0.f);
          x[idx] = v;
          xb[idx] = f2bf(v);
        }
      }
    }
  }
}

// ---- output gather + L2 normalize -------------------------------------------
__global__ void k_out(const float* __restrict__ x, const int* __restrict__ ids,
                      float* __restrict__ out) {
  int b = (blockIdx.x * blockDim.x + threadIdx.x) >> 6;
  int lane = threadIdx.x & 63;
  if (b >= BATCH) return;
  int row = ids[b];
  float v = x[(size_t)row * 64 + lane];
  float s = v * v;
  #pragma unroll
  for (int m = 1; m < 64; m <<= 1) s += __shfl_xor(s, m);
  out[b * 64 + lane] = v / sqrtf(s);
}

extern "C" void kernel_launch(void* const* d_in, const int* in_sizes, int n_in,
                              void* d_out, int out_size, void* d_ws, size_t ws_size,
                              hipStream_t stream) {
  const float* text = (const float*)d_in[0];
  const float* wts  = (const float*)d_in[1];
  const float* Wenc = (const float*)d_in[2];
  const float* benc = (const float*)d_in[3];
  const float* Wsf  = (const float*)d_in[4];
  const float* Wnf  = (const float*)d_in[5];
  const float* bf   = (const float*)d_in[6];
  const float* Wsr  = (const float*)d_in[7];
  const float* Wnr  = (const float*)d_in[8];
  const float* br   = (const float*)d_in[9];
  const int*   src  = (const int*)d_in[10];
  const int*   dst  = (const int*)d_in[11];
  const int*   ids  = (const int*)d_in[12];
  float* out = (float*)d_out;

  char* ws = (char*)d_ws;
  size_t o = 0;
  auto alloc = [&](size_t f32elems) {
    void* p = ws + o;
    o += f32elems * 4;
    o = (o + 255) & ~(size_t)255;
    return p;
  };
  float*  x   = (float*)alloc((size_t)NN * 64);
  ushort* xb  = (ushort*)alloc((size_t)NN * 32);  // bf16 mirror of x
  ushort* nbf = (ushort*)alloc((size_t)NN * 32);  // bf16 neigh fwd; aliased stage_f
  ushort* nbr = (ushort*)alloc((size_t)NN * 32);  // bf16 neigh rev; aliased stage_r
  int2*   cvf = (int2*)alloc((size_t)NE * 2);     // final CSR (col, weight)
  int2*   cvr = (int2*)alloc((size_t)NE * 2);
  int* cm_f    = (int*)alloc((size_t)NBUCK * SBLK);
  int* cm_r    = (int*)alloc((size_t)NBUCK * SBLK);
  int* btot    = (int*)alloc(2 * NBUCK);
  int* bbase_f = (int*)alloc(NBUCK);
  int* bbase_r = (int*)alloc(NBUCK);
  int* startf  = (int*)alloc(NN);
  int* cntf    = (int*)alloc(NN);
  int* startr  = (int*)alloc(NN);
  int* cntr    = (int*)alloc(NN);

  // NN*32 f32-elems (12.8 MB) == NE*2 f32-elems (12.8 MB): exact alias
  int2* stg_f = (int2*)nbf;   // staging dead before gathers write nbf
  int2* stg_r = (int2*)nbr;

  const int EB2 = (NN + 127) / 128;   // 782 blocks (MFMA kernels)

  k_hist2<<<SBLK, 256, 0, stream>>>(src, dst, cm_f, cm_r);
  k_scan1<<<2 * NBUCK, 256, 0, stream>>>(cm_f, cm_r, btot);
  k_scan2<<<1, 512, 0, stream>>>(btot, bbase_f, bbase_r);
  k_scatter2<<<SBLK, 256, 0, stream>>>(src, dst, wts, cm_f, cm_r,
                                       bbase_f, bbase_r, stg_f, stg_r);
  p_build<<<2 * NBUCK, 256, 0, stream>>>(stg_f, btot, bbase_f, startf, cntf, cvf,
                                         stg_r, btot + NBUCK, bbase_r, startr, cntr, cvr);
  k_enc<<<EB2, 256, 0, stream>>>(text, Wenc, benc, x, xb);

  const int GB = ((NN * 32) + 255) / 256;   // 12500 blocks per direction
  for (int l = 0; l < 2; ++l) {
    k_gather2<<<2 * GB, 256, 0, stream>>>(xb, startf, cntf, cvf, nbf,
                                          startr, cntr, cvr, nbr);
    k_layer<<<EB2, 256, 0, stream>>>(xb, nbf, nbr,
                                     Wsf + l * HID * HID, Wnf + l * HID * HID, bf + l * HID,
                                     Wsr + l * HID * HID, Wnr + l * HID * HID, br + l * HID,
                                     x, xb);
  }
  k_out<<<(BATCH * 64) / 256, 256, 0, stream>>>(x, ids, out);
}